// Round 8
// baseline (4441.594 us; speedup 1.0000x reference)
//
#include <hip/hip_runtime.h>
#include <hip/hip_bf16.h>

#define B 16
#define P 1024
#define NPT 16384   // B*P
#define KNN 16
#define MID 96
#define HD 64

// ws layout (in floats)
#define WS_UV   0                        // NPT*192  (aliased as pkeys: NPT*4*16 u64 = 8.4MB < 12.58MB)
#define WS_RN   (WS_UV + NPT*192)        // NPT
#define WS_NBR  (WS_RN + NPT)            // NPT*KNN ints
#define WS_WUV  (WS_NBR + NPT*KNN)       // up to 192*192
#define WS_CVEC (WS_WUV + 192*192)       // 96
#define WS_PART (WS_CVEC + 96)           // B*16*256

#define NCH 4        // chunk lists per row (one per wave)

// ---------------- input MLP: 5 -> 128 -> 128 -> 64, writes cols 192..255 ----
__global__ void k_input(const float* __restrict__ x, const float* __restrict__ dn,
                        const float* __restrict__ w1, const float* __restrict__ b1,
                        const float* __restrict__ w2, const float* __restrict__ b2,
                        const float* __restrict__ w3, const float* __restrict__ b3,
                        float* __restrict__ Hout) {
    __shared__ float xs[8][5];
    __shared__ float t1[8][128];
    __shared__ float t2[8][128];
    int tid = threadIdx.x;            // 128 threads
    int p0 = blockIdx.x * 8;
    if (tid < 40) { int p = tid / 5, f = tid - p * 5; xs[p][f] = x[(p0 + p) * 5 + f] * dn[f]; }
    __syncthreads();
    int c = tid;
    {
        float bb = b1[c];
        #pragma unroll
        for (int p = 0; p < 8; p++) {
            float a = bb;
            #pragma unroll
            for (int f = 0; f < 5; f++) a += xs[p][f] * w1[f * 128 + c];
            t1[p][c] = fmaxf(a, 0.f);
        }
    }
    __syncthreads();
    {
        float acc[8];
        float bb = b2[c];
        #pragma unroll
        for (int p = 0; p < 8; p++) acc[p] = bb;
        for (int k = 0; k < 128; k++) {
            float w = w2[k * 128 + c];
            #pragma unroll
            for (int p = 0; p < 8; p++) acc[p] += t1[p][k] * w;
        }
        #pragma unroll
        for (int p = 0; p < 8; p++) t2[p][c] = fmaxf(acc[p], 0.f);
    }
    __syncthreads();
    if (c < 64) {
        float acc[8];
        float bb = b3[c];
        #pragma unroll
        for (int p = 0; p < 8; p++) acc[p] = bb;
        for (int k = 0; k < 128; k++) {
            float w = w3[k * 64 + c];
            #pragma unroll
            for (int p = 0; p < 8; p++) acc[p] += t2[p][k] * w;
        }
        #pragma unroll
        for (int p = 0; p < 8; p++) Hout[(p0 + p) * 256 + 192 + c] = fmaxf(acc[p], 0.f);
    }
}

// ---------------- per-conv weight prep: WUV = [(top-bot)*s | bot*s], cvec ----
__global__ void k_prep(const float* __restrict__ wa, const float* __restrict__ ba,
                       const float* __restrict__ g, const float* __restrict__ bB,
                       const float* __restrict__ m, const float* __restrict__ v,
                       int D, float* __restrict__ WUV, float* __restrict__ cvec) {
    int idx = blockIdx.x * 256 + threadIdx.x;
    if (idx < D * 192) {
        int k = idx / 192, col = idx - k * 192;
        int ch = (col < 96) ? col : col - 96;
        float s = g[ch] * rsqrtf(v[ch] + 1e-5f);
        float w = (col < 96) ? (wa[k * 96 + ch] - wa[(D + k) * 96 + ch]) : wa[(D + k) * 96 + ch];
        WUV[idx] = w * s;
    }
    if (blockIdx.x == 0 && threadIdx.x < 96) {
        int ch = threadIdx.x;
        float s = g[ch] * rsqrtf(v[ch] + 1e-5f);
        cvec[ch] = ba[ch] * s + (bB[ch] - m[ch] * s);
    }
}

// ---------------- row inverse norms ----------------
__global__ void k_rn(const float* __restrict__ Hout, int colOff, int D, float* __restrict__ rn) {
    int p = blockIdx.x * 256 + threadIdx.x;
    if (p >= NPT) return;
    const float* r = Hout + p * 256 + colOff;
    float ss = 0.f;
    for (int d = 0; d < D; d++) { float v = r[d]; ss += v * v; }
    rn[p] = rsqrtf(ss + 1e-12f);
}

// ------ fused cosine-sim: barrier-free waves, per-thread prefiltered top-16,
// ------ register-only bitonic cross-lane merge, sorted chunk lists ---------
#define XI_LD 196

__device__ __forceinline__ unsigned long long packkey(float v, int q) {
    unsigned u = __float_as_uint(v);
    u = (u & 0x80000000u) ? ~u : (u | 0x80000000u);
    return ((unsigned long long)u << 32) | (unsigned)(1023 - q);
}

// branchless sorted-descending insert; caller guarantees c > kk[15]
__device__ __forceinline__ void ins16(unsigned long long kk[16], unsigned long long c) {
    #pragma unroll
    for (int j = 15; j >= 1; --j)
        kk[j] = (c > kk[j - 1]) ? kk[j - 1] : ((c > kk[j]) ? c : kk[j]);
    kk[0] = (c > kk[0]) ? c : kk[0];
}

template<int ND4>
__global__ void __launch_bounds__(256) k_knn2(const float* __restrict__ Hout, int colOff,
                                              const float* __restrict__ rn,
                                              unsigned long long* __restrict__ pkeys) {
    constexpr int D = ND4 * 4;
    __shared__ __align__(16) float Xi[16 * XI_LD];
    int tid = threadIdx.x;
    int rt = blockIdx.x & 63;
    int b  = blockIdx.x >> 6;
    int i0 = rt * 16;
    for (int idx = tid; idx < 16 * D; idx += 256) {
        int r = idx / D, d = idx - r * D;
        Xi[r * XI_LD + d] = Hout[(size_t)(b * P + i0 + r) * 256 + colOff + d];
    }
    int lane = tid & 63, w = tid >> 6;     // wave w owns candidate chunk w*256..w*256+255
    int i = lane & 15, q4 = lane >> 4;     // row i, 4-cand slice q4 (proven load pattern)
    float rni = rn[b * P + i0 + i];
    int ig = i0 + i;
    const float4* xi4 = (const float4*)(Xi + i * XI_LD);
    unsigned long long kk[16];
    #pragma unroll
    for (int j = 0; j < 16; j++) kk[j] = 0ull;
    __syncthreads();                       // only barrier: Xi ready; waves free-run after
    for (int t = 0; t < 16; t++) {
        int qb = w * 256 + t * 16 + q4 * 4;
        const float4* pq = (const float4*)(Hout + (size_t)(b * P + qb) * 256 + colOff);
        float rq0 = rn[b * P + qb + 0];
        float rq1 = rn[b * P + qb + 1];
        float rq2 = rn[b * P + qb + 2];
        float rq3 = rn[b * P + qb + 3];
        float a0 = 0.f, a1 = 0.f, a2 = 0.f, a3 = 0.f;
        #pragma unroll
        for (int d4 = 0; d4 < ND4; d4++) {
            float4 xv = xi4[d4];
            float4 p0 = pq[d4];
            float4 p1 = pq[64 + d4];
            float4 p2 = pq[128 + d4];
            float4 p3 = pq[192 + d4];
            a0 += xv.x * p0.x; a0 += xv.y * p0.y; a0 += xv.z * p0.z; a0 += xv.w * p0.w;
            a1 += xv.x * p1.x; a1 += xv.y * p1.y; a1 += xv.z * p1.z; a1 += xv.w * p1.w;
            a2 += xv.x * p2.x; a2 += xv.y * p2.y; a2 += xv.z * p2.z; a2 += xv.w * p2.w;
            a3 += xv.x * p3.x; a3 += xv.y * p3.y; a3 += xv.z * p3.z; a3 += xv.w * p3.w;
        }
        float v0 = a0 * rni * rq0;
        float v1 = a1 * rni * rq1;
        float v2 = a2 * rni * rq2;
        float v3 = a3 * rni * rq3;
        if (qb + 0 == ig) v0 = -1e9f;
        if (qb + 1 == ig) v1 = -1e9f;
        if (qb + 2 == ig) v2 = -1e9f;
        if (qb + 3 == ig) v3 = -1e9f;
        unsigned long long c;
        c = packkey(v0, qb + 0); if (c > kk[15]) ins16(kk, c);
        c = packkey(v1, qb + 1); if (c > kk[15]) ins16(kk, c);
        c = packkey(v2, qb + 2); if (c > kk[15]) ins16(kk, c);
        c = packkey(v3, qb + 3); if (c > kk[15]) ins16(kk, c);
    }
    // ---- register-only exact merge of the 4 q4-slice lists (per row) ----
    // round 1: lane ^ 16, round 2: lane ^ 32. Each: top-16 of two sorted-desc
    // 16-lists = {max(a[j], b[15-j])} (bitonic V), then 4-stage bitonic clean.
    #pragma unroll
    for (int dxr = 16; dxr <= 32; dxr <<= 1) {
        unsigned long long m[16];
        #pragma unroll
        for (int j = 0; j < 16; j++) {
            unsigned long long o = __shfl_xor(kk[15 - j], dxr);
            m[j] = kk[j] > o ? kk[j] : o;
        }
        #pragma unroll
        for (int s = 8; s >= 1; s >>= 1) {
            #pragma unroll
            for (int j = 0; j < 16; j++) {
                if ((j & s) == 0) {
                    unsigned long long lo = m[j], hi = m[j | s];
                    m[j]     = lo > hi ? lo : hi;
                    m[j | s] = lo > hi ? hi : lo;
                }
            }
        }
        #pragma unroll
        for (int j = 0; j < 16; j++) kk[j] = m[j];
    }
    // lanes 0..15 hold row i0+lane's chunk top-16 (sorted desc); dump
    if (lane < 16) {
        size_t base = ((size_t)(b * P + i0 + lane) * NCH + w) * 16;
        #pragma unroll
        for (int j = 0; j < 16; j++) pkeys[base + j] = kk[j];
    }
}

// ---- exact merge of per-chunk sorted top-16 lists -> final top-16 ----------
__global__ void __launch_bounds__(256) k_knn_merge(const unsigned long long* __restrict__ pkeys,
                                                   int* __restrict__ nbr) {
    int tid = threadIdx.x;
    int lane = tid & 63, w = tid >> 6;
    int g = lane >> 4, lane16 = lane & 15;
    int row = blockIdx.x * 16 + w * 4 + g;
    int sh = lane & 48;
    // chunk 0's list is already sorted descending across lane16
    unsigned long long listkey = pkeys[((size_t)row * NCH + 0) * 16 + lane16];
    #pragma unroll
    for (int s = 1; s < NCH; s++) {
        unsigned long long cand = pkeys[((size_t)row * NCH + s) * 16 + lane16];
        unsigned long long lmin = __shfl(listkey, 15, 16);
        unsigned long long bal = __ballot(cand > lmin);
        unsigned long long gm = (bal >> sh) & 0xFFFFull;
        while (gm) {
            int src = __builtin_ctzll(gm);
            gm &= gm - 1;
            unsigned long long mv = __shfl(cand, src, 16);
            unsigned long long bal2 = __ballot(listkey > mv);
            int pos = __popcll((bal2 >> sh) & 0xFFFFull);
            unsigned long long up = __shfl_up(listkey, 1, 16);
            if (lane16 == pos) listkey = mv;       // stale cand: pos==16 -> no-op
            else if (lane16 > pos) listkey = up;
        }
    }
    nbr[(size_t)row * KNN + lane16] = 1023 - (int)(listkey & 0xFFFFFFFFull);
}

// ---------------- UV projection: [16384, D] @ [D, 192] ----------------
__global__ void k_uv(const float* __restrict__ Hout, int colOff, int D,
                     const float* __restrict__ WUV, float* __restrict__ UV) {
    __shared__ float Xt[16 * 192];
    int tid = threadIdx.x;   // 192 threads
    int p0 = blockIdx.x * 16;
    for (int idx = tid; idx < 16 * D; idx += 192) {
        int r = idx / D, d = idx - r * D;
        Xt[r * 192 + d] = Hout[(p0 + r) * 256 + colOff + d];
    }
    __syncthreads();
    float acc[16];
    #pragma unroll
    for (int p = 0; p < 16; p++) acc[p] = 0.f;
    for (int k = 0; k < D; k++) {
        float w = WUV[k * 192 + tid];
        #pragma unroll
        for (int p = 0; p < 16; p++) acc[p] += Xt[p * 192 + k] * w;
    }
    #pragma unroll
    for (int p = 0; p < 16; p++) UV[(size_t)(p0 + p) * 192 + tid] = acc[p];
}

// ---------------- per-edge message kernel (wb in VGPRs, no inner barriers) --
__global__ void __launch_bounds__(256) k_edge(const float* __restrict__ UV, const int* __restrict__ nbr,
                                              const float* __restrict__ wb, const float* __restrict__ bbv,
                                              const float* __restrict__ cvec, int colOut,
                                              float* __restrict__ Hout) {
    __shared__ __align__(16) float m1s[4][96];   // wave-private message buffer
    __shared__ float cvs[96];
    __shared__ float bbs[64];
    int tid = threadIdx.x;
    int w = tid >> 6, lane = tid & 63;
    float wreg[96];                              // wb column `lane` in registers
    #pragma unroll
    for (int k = 0; k < 96; k++) wreg[k] = wb[k * 64 + lane];
    if (tid < 96) cvs[tid] = cvec[tid];
    if (tid < 64) bbs[tid] = bbv[tid];
    int ifl = blockIdx.x * 4 + w;
    int b = ifl >> 10, i = ifl & 1023;
    const float* Ui = UV + (size_t)ifl * 192;
    float ui0 = Ui[lane];
    float ui1 = (lane < 32) ? Ui[64 + lane] : 0.f;
    float vi0 = Ui[96 + lane];
    float vi1 = (lane < 32) ? Ui[160 + lane] : 0.f;
    float accA = 0.f;
    __syncthreads();
    float bbl = bbs[lane];
    float cv0 = cvs[lane];
    float cv1 = (lane < 32) ? cvs[64 + lane] : 0.f;
    const float4* m4 = (const float4*)m1s[w];
    for (int kk = 0; kk < KNN; kk++) {
        int j = nbr[ifl * KNN + kk];
        int jf = b * P + j;
        bool mut = __any((lane < KNN) ? (nbr[jf * KNN + lane] == i) : 0);
        const float* Uj = UV + (size_t)jf * 192;
        // forward message: center i, neighbor j   (wave-private -> no barrier)
        m1s[w][lane] = fmaxf(ui0 + Uj[96 + lane] + cv0, 0.f);
        if (lane < 32) m1s[w][64 + lane] = fmaxf(ui1 + Uj[160 + lane] + cv1, 0.f);
        float t = bbl;
        #pragma unroll
        for (int k4 = 0; k4 < 24; k4++) {
            float4 mv = m4[k4];
            t += mv.x * wreg[k4 * 4 + 0];
            t += mv.y * wreg[k4 * 4 + 1];
            t += mv.z * wreg[k4 * 4 + 2];
            t += mv.w * wreg[k4 * 4 + 3];
        }
        accA += fmaxf(t, 0.f);
        // reverse message: center j, neighbor i
        m1s[w][lane] = fmaxf(Uj[lane] + vi0 + cv0, 0.f);
        if (lane < 32) m1s[w][64 + lane] = fmaxf(Uj[64 + lane] + vi1 + cv1, 0.f);
        float t2 = bbl;
        #pragma unroll
        for (int k4 = 0; k4 < 24; k4++) {
            float4 mv = m4[k4];
            t2 += mv.x * wreg[k4 * 4 + 0];
            t2 += mv.y * wreg[k4 * 4 + 1];
            t2 += mv.z * wreg[k4 * 4 + 2];
            t2 += mv.w * wreg[k4 * 4 + 3];
        }
        if (!mut) atomicAdd(&Hout[(size_t)jf * 256 + colOut + lane], fmaxf(t2, 0.f));
    }
    atomicAdd(&Hout[(size_t)ifl * 256 + colOut + lane], accA);
}

// ---------------- global max pool (partial) ----------------
__global__ void k_pool(const float* __restrict__ Hout, float* __restrict__ part) {
    int tid = threadIdx.x;
    int b = blockIdx.x >> 4, pt = blockIdx.x & 15;
    float mv = -1e30f;
    for (int p = pt * 64; p < pt * 64 + 64; p++)
        mv = fmaxf(mv, Hout[(size_t)(b * P + p) * 256 + tid]);
    part[(b * 16 + pt) * 256 + tid] = mv;
}

// ---------------- final reduce + output MLP ----------------
__global__ void k_out(const float* __restrict__ part,
                      const float* __restrict__ w1, const float* __restrict__ b1,
                      const float* __restrict__ w2, const float* __restrict__ b2,
                      const float* __restrict__ w3, const float* __restrict__ b3,
                      float* __restrict__ out) {
    __shared__ float pooled[256];
    __shared__ float r1[128];
    __shared__ float r2[32];
    int tid = threadIdx.x, b = blockIdx.x;
    float mv = -1e30f;
    for (int t = 0; t < 16; t++) mv = fmaxf(mv, part[(b * 16 + t) * 256 + tid]);
    pooled[tid] = mv;
    __syncthreads();
    if (tid < 128) {
        float a = b1[tid];
        for (int k = 0; k < 256; k++) a += pooled[k] * w1[k * 128 + tid];
        r1[tid] = fmaxf(a, 0.f);
    }
    __syncthreads();
    if (tid < 32) {
        float a = b2[tid];
        for (int k = 0; k < 128; k++) a += r1[k] * w2[k * 32 + tid];
        r2[tid] = fmaxf(a, 0.f);
    }
    __syncthreads();
    if (tid == 0) {
        float a = b3[0];
        for (int k = 0; k < 32; k++) a += r2[k] * w3[k];
        out[b] = a;
    }
}

extern "C" void kernel_launch(void* const* d_in, const int* in_sizes, int n_in,
                              void* d_out, int out_size, void* d_ws, size_t ws_size,
                              hipStream_t stream) {
    const float* x  = (const float*)d_in[0];
    const float* dn = (const float*)d_in[1];
    float* out = (float*)d_out;
    float* Hout = out + 16;           // [16384][256] feature/output buffer
    float* ws = (float*)d_ws;
    float* UV   = ws + WS_UV;
    float* rn   = ws + WS_RN;
    int*   nbr  = (int*)(ws + WS_NBR);
    float* WUV  = ws + WS_WUV;
    float* cvec = ws + WS_CVEC;
    float* part = ws + WS_PART;
    unsigned long long* pkeys = (unsigned long long*)UV;   // aliased: dead before k_uv

    hipMemsetAsync(d_out, 0, (size_t)out_size * sizeof(float), stream);

    k_input<<<2048, 128, 0, stream>>>(x, dn,
        (const float*)d_in[2], (const float*)d_in[3],
        (const float*)d_in[4], (const float*)d_in[5],
        (const float*)d_in[6], (const float*)d_in[7], Hout);

    const int convOff[3] = {192, 128, 64};   // input column offset
    const int convD[3]   = {64, 128, 192};   // input feature width
    const int convOut[3] = {128, 64, 0};     // output column offset
    for (int c = 0; c < 3; c++) {
        int pb = 8 + c * 8;
        const float* wa  = (const float*)d_in[pb + 0];
        const float* ba  = (const float*)d_in[pb + 1];
        const float* g   = (const float*)d_in[pb + 2];
        const float* bB  = (const float*)d_in[pb + 3];
        const float* m   = (const float*)d_in[pb + 4];
        const float* v   = (const float*)d_in[pb + 5];
        const float* wb  = (const float*)d_in[pb + 6];
        const float* bbv = (const float*)d_in[pb + 7];
        int D = convD[c], off = convOff[c], co = convOut[c];
        k_prep<<<(D * 192 + 255) / 256, 256, 0, stream>>>(wa, ba, g, bB, m, v, D, WUV, cvec);
        k_rn<<<64, 256, 0, stream>>>(Hout, off, D, rn);
        if (c == 0)      k_knn2<16><<<1024, 256, 0, stream>>>(Hout, off, rn, pkeys);
        else if (c == 1) k_knn2<32><<<1024, 256, 0, stream>>>(Hout, off, rn, pkeys);
        else             k_knn2<48><<<1024, 256, 0, stream>>>(Hout, off, rn, pkeys);
        k_knn_merge<<<1024, 256, 0, stream>>>(pkeys, nbr);
        k_uv<<<1024, 192, 0, stream>>>(Hout, off, D, WUV, UV);
        k_edge<<<4096, 256, 0, stream>>>(UV, nbr, wb, bbv, cvec, co, Hout);
    }

    k_pool<<<256, 256, 0, stream>>>(Hout, part);
    k_out<<<16, 256, 0, stream>>>(part,
        (const float*)d_in[32], (const float*)d_in[33],
        (const float*)d_in[34], (const float*)d_in[35],
        (const float*)d_in[36], (const float*)d_in[37], out);
}

// Round 9
// 1458.668 us; speedup vs baseline: 3.0450x; 3.0450x over previous
//
#include <hip/hip_runtime.h>
#include <hip/hip_bf16.h>

#define B 16
#define P 1024
#define NPT 16384   // B*P
#define KNN 16
#define MID 96
#define HD 64

// ws layout (in floats)
#define WS_UV   0                        // NPT*192  (aliased as pkeys: NPT*4*16 u64 = 8.4MB < 12.58MB)
#define WS_RN   (WS_UV + NPT*192)        // NPT
#define WS_NBR  (WS_RN + NPT)            // NPT*KNN ints
#define WS_WUV  (WS_NBR + NPT*KNN)       // up to 192*192
#define WS_CVEC (WS_WUV + 192*192)       // 96
#define WS_PART (WS_CVEC + 96)           // B*16*256
#define WS_XT   (WS_PART + 16*16*256)    // B*192*1024 floats (transposed features)

#define NCH 4        // chunk lists per row

// ---------------- input MLP: 5 -> 128 -> 128 -> 64, writes cols 192..255 ----
__global__ void k_input(const float* __restrict__ x, const float* __restrict__ dn,
                        const float* __restrict__ w1, const float* __restrict__ b1,
                        const float* __restrict__ w2, const float* __restrict__ b2,
                        const float* __restrict__ w3, const float* __restrict__ b3,
                        float* __restrict__ Hout) {
    __shared__ float xs[8][5];
    __shared__ float t1[8][128];
    __shared__ float t2[8][128];
    int tid = threadIdx.x;            // 128 threads
    int p0 = blockIdx.x * 8;
    if (tid < 40) { int p = tid / 5, f = tid - p * 5; xs[p][f] = x[(p0 + p) * 5 + f] * dn[f]; }
    __syncthreads();
    int c = tid;
    {
        float bb = b1[c];
        #pragma unroll
        for (int p = 0; p < 8; p++) {
            float a = bb;
            #pragma unroll
            for (int f = 0; f < 5; f++) a += xs[p][f] * w1[f * 128 + c];
            t1[p][c] = fmaxf(a, 0.f);
        }
    }
    __syncthreads();
    {
        float acc[8];
        float bb = b2[c];
        #pragma unroll
        for (int p = 0; p < 8; p++) acc[p] = bb;
        for (int k = 0; k < 128; k++) {
            float w = w2[k * 128 + c];
            #pragma unroll
            for (int p = 0; p < 8; p++) acc[p] += t1[p][k] * w;
        }
        #pragma unroll
        for (int p = 0; p < 8; p++) t2[p][c] = fmaxf(acc[p], 0.f);
    }
    __syncthreads();
    if (c < 64) {
        float acc[8];
        float bb = b3[c];
        #pragma unroll
        for (int p = 0; p < 8; p++) acc[p] = bb;
        for (int k = 0; k < 128; k++) {
            float w = w3[k * 64 + c];
            #pragma unroll
            for (int p = 0; p < 8; p++) acc[p] += t2[p][k] * w;
        }
        #pragma unroll
        for (int p = 0; p < 8; p++) Hout[(p0 + p) * 256 + 192 + c] = fmaxf(acc[p], 0.f);
    }
}

// ---------------- per-conv weight prep: WUV = [(top-bot)*s | bot*s], cvec ----
__global__ void k_prep(const float* __restrict__ wa, const float* __restrict__ ba,
                       const float* __restrict__ g, const float* __restrict__ bB,
                       const float* __restrict__ m, const float* __restrict__ v,
                       int D, float* __restrict__ WUV, float* __restrict__ cvec) {
    int idx = blockIdx.x * 256 + threadIdx.x;
    if (idx < D * 192) {
        int k = idx / 192, col = idx - k * 192;
        int ch = (col < 96) ? col : col - 96;
        float s = g[ch] * rsqrtf(v[ch] + 1e-5f);
        float w = (col < 96) ? (wa[k * 96 + ch] - wa[(D + k) * 96 + ch]) : wa[(D + k) * 96 + ch];
        WUV[idx] = w * s;
    }
    if (blockIdx.x == 0 && threadIdx.x < 96) {
        int ch = threadIdx.x;
        float s = g[ch] * rsqrtf(v[ch] + 1e-5f);
        cvec[ch] = ba[ch] * s + (bB[ch] - m[ch] * s);
    }
}

// ---------------- row inverse norms ----------------
__global__ void k_rn(const float* __restrict__ Hout, int colOff, int D, float* __restrict__ rn) {
    int p = blockIdx.x * 256 + threadIdx.x;
    if (p >= NPT) return;
    const float* r = Hout + p * 256 + colOff;
    float ss = 0.f;
    for (int d = 0; d < D; d++) { float v = r[d]; ss += v * v; }
    rn[p] = rsqrtf(ss + 1e-12f);
}

// ---------------- per-batch feature transpose: Xt[b][d][1024] ----------------
__global__ void __launch_bounds__(256) k_tr(const float* __restrict__ Hout, int colOff, int D,
                                            float* __restrict__ Xt) {
    __shared__ float t[64][65];
    int tid = threadIdx.x;
    int d0 = blockIdx.x * 64, p0 = blockIdx.y * 64, b = blockIdx.z;
    int r4 = tid >> 6, c = tid & 63;
    #pragma unroll
    for (int k = 0; k < 16; k++) {
        int row = k * 4 + r4;
        t[row][c] = Hout[(size_t)(b * P + p0 + row) * 256 + colOff + d0 + c];
    }
    __syncthreads();
    #pragma unroll
    for (int k = 0; k < 16; k++) {
        int d = k * 4 + r4;
        Xt[((size_t)b * D + d0 + d) * 1024 + p0 + c] = t[c][d];
    }
}

// ------ GEMM-style cosine-sim (coalesced Xt) + R4 ballot blind-insert -------
#define ST_LD 260

__device__ __forceinline__ unsigned long long packkey(float v, int q) {
    unsigned u = __float_as_uint(v);
    u = (u & 0x80000000u) ? ~u : (u | 0x80000000u);
    return ((unsigned long long)u << 32) | (unsigned)(1023 - q);
}

template<int D>
__global__ void __launch_bounds__(256) k_knn3(const float* __restrict__ Xt,
                                              const float* __restrict__ rn,
                                              unsigned long long* __restrict__ pkeys) {
    __shared__ __align__(16) float XiT[D * 20];          // [d][16 rows], pad 20
    __shared__ __align__(16) float simtile[16 * ST_LD];  // [16 rows][256 cands]
    int tid = threadIdx.x;
    int chunk = blockIdx.x & 3, rt = (blockIdx.x >> 2) & 63, b = blockIdx.x >> 8;
    int i0 = rt * 16, q0 = chunk * 256;
    int lane = tid & 63, w = tid >> 6;
    // stage XiT (row tile, transposed)
    for (int idx = tid; idx < 16 * D; idx += 256) {
        int d = idx >> 4, r = idx & 15;
        XiT[d * 20 + r] = Xt[((size_t)b * D + d) * 1024 + i0 + r];
    }
    __syncthreads();
    // ---- compute: thread = rows 4w..4w+3 x cands q0+4*lane..+3 ----
    const float* cvb = Xt + (size_t)b * D * 1024 + q0 + 4 * lane;
    float acc[4][4] = {};
    #pragma unroll 8
    for (int d = 0; d < D; d++) {
        float4 cv = *(const float4*)(cvb + (size_t)d * 1024);
        float4 rv = *(const float4*)(XiT + d * 20 + 4 * w);
        acc[0][0] += rv.x * cv.x; acc[0][1] += rv.x * cv.y; acc[0][2] += rv.x * cv.z; acc[0][3] += rv.x * cv.w;
        acc[1][0] += rv.y * cv.x; acc[1][1] += rv.y * cv.y; acc[1][2] += rv.y * cv.z; acc[1][3] += rv.y * cv.w;
        acc[2][0] += rv.z * cv.x; acc[2][1] += rv.z * cv.y; acc[2][2] += rv.z * cv.z; acc[2][3] += rv.z * cv.w;
        acc[3][0] += rv.w * cv.x; acc[3][1] += rv.w * cv.y; acc[3][2] += rv.w * cv.z; acc[3][3] += rv.w * cv.w;
    }
    float4 rq = *(const float4*)(rn + b * P + q0 + 4 * lane);
    int qg = q0 + 4 * lane;
    #pragma unroll
    for (int r = 0; r < 4; r++) {
        float rnir = rn[b * P + i0 + 4 * w + r];
        int ig = i0 + 4 * w + r;
        float4 v;
        v.x = acc[r][0] * rnir * rq.x;
        v.y = acc[r][1] * rnir * rq.y;
        v.z = acc[r][2] * rnir * rq.z;
        v.w = acc[r][3] * rnir * rq.w;
        if (qg + 0 == ig) v.x = -1e9f;
        if (qg + 1 == ig) v.y = -1e9f;
        if (qg + 2 == ig) v.z = -1e9f;
        if (qg + 3 == ig) v.w = -1e9f;
        *(float4*)(simtile + (4 * w + r) * ST_LD + 4 * lane) = v;
    }
    __syncthreads();
    // ---- R4 ballot-filter + blind-insert: 16-lane group per row, 4 tiles ----
    int g = lane >> 4, lane16 = lane & 15;
    int row = w * 4 + g;
    int sh = lane & 48;
    unsigned long long listkey = 0ull;
    for (int t = 0; t < 4; t++) {
        int qb = q0 + t * 64;
        unsigned long long c0 = packkey(simtile[row * ST_LD + t * 64 + lane16     ], qb + lane16);
        unsigned long long c1 = packkey(simtile[row * ST_LD + t * 64 + lane16 + 16], qb + lane16 + 16);
        unsigned long long c2 = packkey(simtile[row * ST_LD + t * 64 + lane16 + 32], qb + lane16 + 32);
        unsigned long long c3 = packkey(simtile[row * ST_LD + t * 64 + lane16 + 48], qb + lane16 + 48);
        unsigned long long lmin = __shfl(listkey, 15, 16);
        unsigned long long b0 = __ballot(c0 > lmin);
        unsigned long long b1 = __ballot(c1 > lmin);
        unsigned long long b2 = __ballot(c2 > lmin);
        unsigned long long b3 = __ballot(c3 > lmin);
        unsigned long long gm = ((b0 >> sh) & 0xFFFFull)
                              | (((b1 >> sh) & 0xFFFFull) << 16)
                              | (((b2 >> sh) & 0xFFFFull) << 32)
                              | (((b3 >> sh) & 0xFFFFull) << 48);
        // stale (too-small) candidates self-discard (pos==16 -> no-op)
        while (gm) {
            int pb = __builtin_ctzll(gm);
            gm &= gm - 1;
            int slot = pb >> 4, src = pb & 15;
            unsigned long long sel = (slot & 2) ? ((slot & 1) ? c3 : c2)
                                                : ((slot & 1) ? c1 : c0);
            unsigned long long mv = __shfl(sel, src, 16);
            unsigned long long bal = __ballot(listkey > mv);
            int pos = __popcll((bal >> sh) & 0xFFFFull);
            unsigned long long up = __shfl_up(listkey, 1, 16);
            if (lane16 == pos) listkey = mv;
            else if (lane16 > pos) listkey = up;
        }
    }
    pkeys[(((size_t)(b * P + i0 + row)) * NCH + chunk) * 16 + lane16] = listkey;
}

// ---- exact merge of per-chunk sorted top-16 lists -> final top-16 ----------
__global__ void __launch_bounds__(256) k_knn_merge(const unsigned long long* __restrict__ pkeys,
                                                   int* __restrict__ nbr) {
    int tid = threadIdx.x;
    int lane = tid & 63, w = tid >> 6;
    int g = lane >> 4, lane16 = lane & 15;
    int row = blockIdx.x * 16 + w * 4 + g;
    int sh = lane & 48;
    // chunk 0's list is already sorted descending across lane16
    unsigned long long listkey = pkeys[((size_t)row * NCH + 0) * 16 + lane16];
    #pragma unroll
    for (int s = 1; s < NCH; s++) {
        unsigned long long cand = pkeys[((size_t)row * NCH + s) * 16 + lane16];
        unsigned long long lmin = __shfl(listkey, 15, 16);
        unsigned long long bal = __ballot(cand > lmin);
        unsigned long long gm = (bal >> sh) & 0xFFFFull;
        while (gm) {
            int src = __builtin_ctzll(gm);
            gm &= gm - 1;
            unsigned long long mv = __shfl(cand, src, 16);
            unsigned long long bal2 = __ballot(listkey > mv);
            int pos = __popcll((bal2 >> sh) & 0xFFFFull);
            unsigned long long up = __shfl_up(listkey, 1, 16);
            if (lane16 == pos) listkey = mv;       // stale cand: pos==16 -> no-op
            else if (lane16 > pos) listkey = up;
        }
    }
    nbr[(size_t)row * KNN + lane16] = 1023 - (int)(listkey & 0xFFFFFFFFull);
}

// ---------------- UV projection: [16384, D] @ [D, 192] ----------------
__global__ void k_uv(const float* __restrict__ Hout, int colOff, int D,
                     const float* __restrict__ WUV, float* __restrict__ UV) {
    __shared__ float Xt[16 * 192];
    int tid = threadIdx.x;   // 192 threads
    int p0 = blockIdx.x * 16;
    for (int idx = tid; idx < 16 * D; idx += 192) {
        int r = idx / D, d = idx - r * D;
        Xt[r * 192 + d] = Hout[(p0 + r) * 256 + colOff + d];
    }
    __syncthreads();
    float acc[16];
    #pragma unroll
    for (int p = 0; p < 16; p++) acc[p] = 0.f;
    for (int k = 0; k < D; k++) {
        float w = WUV[k * 192 + tid];
        #pragma unroll
        for (int p = 0; p < 16; p++) acc[p] += Xt[p * 192 + k] * w;
    }
    #pragma unroll
    for (int p = 0; p < 16; p++) UV[(size_t)(p0 + p) * 192 + tid] = acc[p];
}

// ---------------- per-edge message kernel (wb in VGPRs, no inner barriers) --
__global__ void __launch_bounds__(256) k_edge(const float* __restrict__ UV, const int* __restrict__ nbr,
                                              const float* __restrict__ wb, const float* __restrict__ bbv,
                                              const float* __restrict__ cvec, int colOut,
                                              float* __restrict__ Hout) {
    __shared__ __align__(16) float m1s[4][96];   // wave-private message buffer
    __shared__ float cvs[96];
    __shared__ float bbs[64];
    int tid = threadIdx.x;
    int w = tid >> 6, lane = tid & 63;
    float wreg[96];                              // wb column `lane` in registers
    #pragma unroll
    for (int k = 0; k < 96; k++) wreg[k] = wb[k * 64 + lane];
    if (tid < 96) cvs[tid] = cvec[tid];
    if (tid < 64) bbs[tid] = bbv[tid];
    int ifl = blockIdx.x * 4 + w;
    int b = ifl >> 10, i = ifl & 1023;
    const float* Ui = UV + (size_t)ifl * 192;
    float ui0 = Ui[lane];
    float ui1 = (lane < 32) ? Ui[64 + lane] : 0.f;
    float vi0 = Ui[96 + lane];
    float vi1 = (lane < 32) ? Ui[160 + lane] : 0.f;
    float accA = 0.f;
    __syncthreads();
    float bbl = bbs[lane];
    float cv0 = cvs[lane];
    float cv1 = (lane < 32) ? cvs[64 + lane] : 0.f;
    const float4* m4 = (const float4*)m1s[w];
    for (int kk = 0; kk < KNN; kk++) {
        int j = nbr[ifl * KNN + kk];
        int jf = b * P + j;
        bool mut = __any((lane < KNN) ? (nbr[jf * KNN + lane] == i) : 0);
        const float* Uj = UV + (size_t)jf * 192;
        // forward message: center i, neighbor j   (wave-private -> no barrier)
        m1s[w][lane] = fmaxf(ui0 + Uj[96 + lane] + cv0, 0.f);
        if (lane < 32) m1s[w][64 + lane] = fmaxf(ui1 + Uj[160 + lane] + cv1, 0.f);
        float t = bbl;
        #pragma unroll
        for (int k4 = 0; k4 < 24; k4++) {
            float4 mv = m4[k4];
            t += mv.x * wreg[k4 * 4 + 0];
            t += mv.y * wreg[k4 * 4 + 1];
            t += mv.z * wreg[k4 * 4 + 2];
            t += mv.w * wreg[k4 * 4 + 3];
        }
        accA += fmaxf(t, 0.f);
        // reverse message: center j, neighbor i
        m1s[w][lane] = fmaxf(Uj[lane] + vi0 + cv0, 0.f);
        if (lane < 32) m1s[w][64 + lane] = fmaxf(Uj[64 + lane] + vi1 + cv1, 0.f);
        float t2 = bbl;
        #pragma unroll
        for (int k4 = 0; k4 < 24; k4++) {
            float4 mv = m4[k4];
            t2 += mv.x * wreg[k4 * 4 + 0];
            t2 += mv.y * wreg[k4 * 4 + 1];
            t2 += mv.z * wreg[k4 * 4 + 2];
            t2 += mv.w * wreg[k4 * 4 + 3];
        }
        if (!mut) atomicAdd(&Hout[(size_t)jf * 256 + colOut + lane], fmaxf(t2, 0.f));
    }
    atomicAdd(&Hout[(size_t)ifl * 256 + colOut + lane], accA);
}

// ---------------- global max pool (partial) ----------------
__global__ void k_pool(const float* __restrict__ Hout, float* __restrict__ part) {
    int tid = threadIdx.x;
    int b = blockIdx.x >> 4, pt = blockIdx.x & 15;
    float mv = -1e30f;
    for (int p = pt * 64; p < pt * 64 + 64; p++)
        mv = fmaxf(mv, Hout[(size_t)(b * P + p) * 256 + tid]);
    part[(b * 16 + pt) * 256 + tid] = mv;
}

// ---------------- final reduce + output MLP ----------------
__global__ void k_out(const float* __restrict__ part,
                      const float* __restrict__ w1, const float* __restrict__ b1,
                      const float* __restrict__ w2, const float* __restrict__ b2,
                      const float* __restrict__ w3, const float* __restrict__ b3,
                      float* __restrict__ out) {
    __shared__ float pooled[256];
    __shared__ float r1[128];
    __shared__ float r2[32];
    int tid = threadIdx.x, b = blockIdx.x;
    float mv = -1e30f;
    for (int t = 0; t < 16; t++) mv = fmaxf(mv, part[(b * 16 + t) * 256 + tid]);
    pooled[tid] = mv;
    __syncthreads();
    if (tid < 128) {
        float a = b1[tid];
        for (int k = 0; k < 256; k++) a += pooled[k] * w1[k * 128 + tid];
        r1[tid] = fmaxf(a, 0.f);
    }
    __syncthreads();
    if (tid < 32) {
        float a = b2[tid];
        for (int k = 0; k < 128; k++) a += r1[k] * w2[k * 32 + tid];
        r2[tid] = fmaxf(a, 0.f);
    }
    __syncthreads();
    if (tid == 0) {
        float a = b3[0];
        for (int k = 0; k < 32; k++) a += r2[k] * w3[k];
        out[b] = a;
    }
}

extern "C" void kernel_launch(void* const* d_in, const int* in_sizes, int n_in,
                              void* d_out, int out_size, void* d_ws, size_t ws_size,
                              hipStream_t stream) {
    const float* x  = (const float*)d_in[0];
    const float* dn = (const float*)d_in[1];
    float* out = (float*)d_out;
    float* Hout = out + 16;           // [16384][256] feature/output buffer
    float* ws = (float*)d_ws;
    float* UV   = ws + WS_UV;
    float* rn   = ws + WS_RN;
    int*   nbr  = (int*)(ws + WS_NBR);
    float* WUV  = ws + WS_WUV;
    float* cvec = ws + WS_CVEC;
    float* part = ws + WS_PART;
    float* Xt   = ws + WS_XT;
    unsigned long long* pkeys = (unsigned long long*)UV;   // aliased: dead before k_uv

    hipMemsetAsync(d_out, 0, (size_t)out_size * sizeof(float), stream);

    k_input<<<2048, 128, 0, stream>>>(x, dn,
        (const float*)d_in[2], (const float*)d_in[3],
        (const float*)d_in[4], (const float*)d_in[5],
        (const float*)d_in[6], (const float*)d_in[7], Hout);

    const int convOff[3] = {192, 128, 64};   // input column offset
    const int convD[3]   = {64, 128, 192};   // input feature width
    const int convOut[3] = {128, 64, 0};     // output column offset
    for (int c = 0; c < 3; c++) {
        int pb = 8 + c * 8;
        const float* wa  = (const float*)d_in[pb + 0];
        const float* ba  = (const float*)d_in[pb + 1];
        const float* g   = (const float*)d_in[pb + 2];
        const float* bB  = (const float*)d_in[pb + 3];
        const float* m   = (const float*)d_in[pb + 4];
        const float* v   = (const float*)d_in[pb + 5];
        const float* wb  = (const float*)d_in[pb + 6];
        const float* bbv = (const float*)d_in[pb + 7];
        int D = convD[c], off = convOff[c], co = convOut[c];
        k_prep<<<(D * 192 + 255) / 256, 256, 0, stream>>>(wa, ba, g, bB, m, v, D, WUV, cvec);
        k_rn<<<64, 256, 0, stream>>>(Hout, off, D, rn);
        k_tr<<<dim3(D / 64, P / 64, B), 256, 0, stream>>>(Hout, off, D, Xt);
        if (c == 0)      k_knn3<64><<<4096, 256, 0, stream>>>(Xt, rn, pkeys);
        else if (c == 1) k_knn3<128><<<4096, 256, 0, stream>>>(Xt, rn, pkeys);
        else             k_knn3<192><<<4096, 256, 0, stream>>>(Xt, rn, pkeys);
        k_knn_merge<<<1024, 256, 0, stream>>>(pkeys, nbr);
        k_uv<<<1024, 192, 0, stream>>>(Hout, off, D, WUV, UV);
        k_edge<<<4096, 256, 0, stream>>>(UV, nbr, wb, bbv, cvec, co, Hout);
    }

    k_pool<<<256, 256, 0, stream>>>(Hout, part);
    k_out<<<16, 256, 0, stream>>>(part,
        (const float*)d_in[32], (const float*)d_in[33],
        (const float*)d_in[34], (const float*)d_in[35],
        (const float*)d_in[36], (const float*)d_in[37], out);
}

// Round 10
// 1145.818 us; speedup vs baseline: 3.8764x; 1.2730x over previous
//
#include <hip/hip_runtime.h>
#include <hip/hip_bf16.h>

#define B 16
#define P 1024
#define NPT 16384   // B*P
#define KNN 16
#define MID 96
#define HD 64

// ws layout (in floats)
#define WS_UV   0                        // NPT*192  (aliased as pkeys: NPT*4*16 u64 = 8.4MB < 12.58MB)
#define WS_RN   (WS_UV + NPT*192)        // NPT
#define WS_NBR  (WS_RN + NPT)            // NPT*KNN ints
#define WS_WUV  (WS_NBR + NPT*KNN)       // up to 192*192
#define WS_CVEC (WS_WUV + 192*192)       // 96
#define WS_PART (WS_CVEC + 96)           // B*16*256
#define WS_XT   (WS_PART + 16*16*256)    // B*192*1024 floats (transposed features)

#define NCH 4        // chunk lists per row

// ---------------- input MLP: 5 -> 128 -> 128 -> 64, writes cols 192..255 ----
__global__ void k_input(const float* __restrict__ x, const float* __restrict__ dn,
                        const float* __restrict__ w1, const float* __restrict__ b1,
                        const float* __restrict__ w2, const float* __restrict__ b2,
                        const float* __restrict__ w3, const float* __restrict__ b3,
                        float* __restrict__ Hout) {
    __shared__ float xs[8][5];
    __shared__ float t1[8][128];
    __shared__ float t2[8][128];
    int tid = threadIdx.x;            // 128 threads
    int p0 = blockIdx.x * 8;
    if (tid < 40) { int p = tid / 5, f = tid - p * 5; xs[p][f] = x[(p0 + p) * 5 + f] * dn[f]; }
    __syncthreads();
    int c = tid;
    {
        float bb = b1[c];
        #pragma unroll
        for (int p = 0; p < 8; p++) {
            float a = bb;
            #pragma unroll
            for (int f = 0; f < 5; f++) a += xs[p][f] * w1[f * 128 + c];
            t1[p][c] = fmaxf(a, 0.f);
        }
    }
    __syncthreads();
    {
        float acc[8];
        float bb = b2[c];
        #pragma unroll
        for (int p = 0; p < 8; p++) acc[p] = bb;
        for (int k = 0; k < 128; k++) {
            float w = w2[k * 128 + c];
            #pragma unroll
            for (int p = 0; p < 8; p++) acc[p] += t1[p][k] * w;
        }
        #pragma unroll
        for (int p = 0; p < 8; p++) t2[p][c] = fmaxf(acc[p], 0.f);
    }
    __syncthreads();
    if (c < 64) {
        float acc[8];
        float bb = b3[c];
        #pragma unroll
        for (int p = 0; p < 8; p++) acc[p] = bb;
        for (int k = 0; k < 128; k++) {
            float w = w3[k * 64 + c];
            #pragma unroll
            for (int p = 0; p < 8; p++) acc[p] += t2[p][k] * w;
        }
        #pragma unroll
        for (int p = 0; p < 8; p++) Hout[(p0 + p) * 256 + 192 + c] = fmaxf(acc[p], 0.f);
    }
}

// ---------------- per-conv weight prep: WUV = [(top-bot)*s | bot*s], cvec ----
__global__ void k_prep(const float* __restrict__ wa, const float* __restrict__ ba,
                       const float* __restrict__ g, const float* __restrict__ bB,
                       const float* __restrict__ m, const float* __restrict__ v,
                       int D, float* __restrict__ WUV, float* __restrict__ cvec) {
    int idx = blockIdx.x * 256 + threadIdx.x;
    if (idx < D * 192) {
        int k = idx / 192, col = idx - k * 192;
        int ch = (col < 96) ? col : col - 96;
        float s = g[ch] * rsqrtf(v[ch] + 1e-5f);
        float w = (col < 96) ? (wa[k * 96 + ch] - wa[(D + k) * 96 + ch]) : wa[(D + k) * 96 + ch];
        WUV[idx] = w * s;
    }
    if (blockIdx.x == 0 && threadIdx.x < 96) {
        int ch = threadIdx.x;
        float s = g[ch] * rsqrtf(v[ch] + 1e-5f);
        cvec[ch] = ba[ch] * s + (bB[ch] - m[ch] * s);
    }
}

// ---------------- row inverse norms ----------------
__global__ void k_rn(const float* __restrict__ Hout, int colOff, int D, float* __restrict__ rn) {
    int p = blockIdx.x * 256 + threadIdx.x;
    if (p >= NPT) return;
    const float* r = Hout + p * 256 + colOff;
    float ss = 0.f;
    for (int d = 0; d < D; d++) { float v = r[d]; ss += v * v; }
    rn[p] = rsqrtf(ss + 1e-12f);
}

// ---------------- per-batch feature transpose: Xt[b][d][1024] ----------------
__global__ void __launch_bounds__(256) k_tr(const float* __restrict__ Hout, int colOff, int D,
                                            float* __restrict__ Xt) {
    __shared__ float t[64][65];
    int tid = threadIdx.x;
    int d0 = blockIdx.x * 64, p0 = blockIdx.y * 64, b = blockIdx.z;
    int r4 = tid >> 6, c = tid & 63;
    #pragma unroll
    for (int k = 0; k < 16; k++) {
        int row = k * 4 + r4;
        t[row][c] = Hout[(size_t)(b * P + p0 + row) * 256 + colOff + d0 + c];
    }
    __syncthreads();
    #pragma unroll
    for (int k = 0; k < 16; k++) {
        int d = k * 4 + r4;
        Xt[((size_t)b * D + d0 + d) * 1024 + p0 + c] = t[c][d];
    }
}

// ------ GEMM-style cosine-sim (coalesced Xt) + R4 ballot blind-insert -------
#define ST_LD 260

__device__ __forceinline__ unsigned long long packkey(float v, int q) {
    unsigned u = __float_as_uint(v);
    u = (u & 0x80000000u) ? ~u : (u | 0x80000000u);
    return ((unsigned long long)u << 32) | (unsigned)(1023 - q);
}

template<int D>
__global__ void __launch_bounds__(256) k_knn3(const float* __restrict__ Xt,
                                              const float* __restrict__ rn,
                                              unsigned long long* __restrict__ pkeys) {
    __shared__ __align__(16) float XiT[D * 20];          // [d][16 rows], pad 20
    __shared__ __align__(16) float simtile[16 * ST_LD];  // [16 rows][256 cands]
    int tid = threadIdx.x;
    int chunk = blockIdx.x & 3, rt = (blockIdx.x >> 2) & 63, b = blockIdx.x >> 8;
    int i0 = rt * 16, q0 = chunk * 256;
    int lane = tid & 63, w = tid >> 6;
    // stage XiT (row tile, transposed)
    for (int idx = tid; idx < 16 * D; idx += 256) {
        int d = idx >> 4, r = idx & 15;
        XiT[d * 20 + r] = Xt[((size_t)b * D + d) * 1024 + i0 + r];
    }
    __syncthreads();
    // ---- compute: thread = rows 4w..4w+3 x cands q0+4*lane..+3 ----
    const float* cvb = Xt + (size_t)b * D * 1024 + q0 + 4 * lane;
    float acc[4][4] = {};
    #pragma unroll 8
    for (int d = 0; d < D; d++) {
        float4 cv = *(const float4*)(cvb + (size_t)d * 1024);
        float4 rv = *(const float4*)(XiT + d * 20 + 4 * w);
        acc[0][0] += rv.x * cv.x; acc[0][1] += rv.x * cv.y; acc[0][2] += rv.x * cv.z; acc[0][3] += rv.x * cv.w;
        acc[1][0] += rv.y * cv.x; acc[1][1] += rv.y * cv.y; acc[1][2] += rv.y * cv.z; acc[1][3] += rv.y * cv.w;
        acc[2][0] += rv.z * cv.x; acc[2][1] += rv.z * cv.y; acc[2][2] += rv.z * cv.z; acc[2][3] += rv.z * cv.w;
        acc[3][0] += rv.w * cv.x; acc[3][1] += rv.w * cv.y; acc[3][2] += rv.w * cv.z; acc[3][3] += rv.w * cv.w;
    }
    float4 rq = *(const float4*)(rn + b * P + q0 + 4 * lane);
    int qg = q0 + 4 * lane;
    #pragma unroll
    for (int r = 0; r < 4; r++) {
        float rnir = rn[b * P + i0 + 4 * w + r];
        int ig = i0 + 4 * w + r;
        float4 v;
        v.x = acc[r][0] * rnir * rq.x;
        v.y = acc[r][1] * rnir * rq.y;
        v.z = acc[r][2] * rnir * rq.z;
        v.w = acc[r][3] * rnir * rq.w;
        if (qg + 0 == ig) v.x = -1e9f;
        if (qg + 1 == ig) v.y = -1e9f;
        if (qg + 2 == ig) v.z = -1e9f;
        if (qg + 3 == ig) v.w = -1e9f;
        *(float4*)(simtile + (4 * w + r) * ST_LD + 4 * lane) = v;
    }
    __syncthreads();
    // ---- R4 ballot-filter + blind-insert: 16-lane group per row, 4 tiles ----
    int g = lane >> 4, lane16 = lane & 15;
    int row = w * 4 + g;
    int sh = lane & 48;
    unsigned long long listkey = 0ull;
    for (int t = 0; t < 4; t++) {
        int qb = q0 + t * 64;
        unsigned long long c0 = packkey(simtile[row * ST_LD + t * 64 + lane16     ], qb + lane16);
        unsigned long long c1 = packkey(simtile[row * ST_LD + t * 64 + lane16 + 16], qb + lane16 + 16);
        unsigned long long c2 = packkey(simtile[row * ST_LD + t * 64 + lane16 + 32], qb + lane16 + 32);
        unsigned long long c3 = packkey(simtile[row * ST_LD + t * 64 + lane16 + 48], qb + lane16 + 48);
        unsigned long long lmin = __shfl(listkey, 15, 16);
        unsigned long long b0 = __ballot(c0 > lmin);
        unsigned long long b1 = __ballot(c1 > lmin);
        unsigned long long b2 = __ballot(c2 > lmin);
        unsigned long long b3 = __ballot(c3 > lmin);
        unsigned long long gm = ((b0 >> sh) & 0xFFFFull)
                              | (((b1 >> sh) & 0xFFFFull) << 16)
                              | (((b2 >> sh) & 0xFFFFull) << 32)
                              | (((b3 >> sh) & 0xFFFFull) << 48);
        // stale (too-small) candidates self-discard (pos==16 -> no-op)
        while (gm) {
            int pb = __builtin_ctzll(gm);
            gm &= gm - 1;
            int slot = pb >> 4, src = pb & 15;
            unsigned long long sel = (slot & 2) ? ((slot & 1) ? c3 : c2)
                                                : ((slot & 1) ? c1 : c0);
            unsigned long long mv = __shfl(sel, src, 16);
            unsigned long long bal = __ballot(listkey > mv);
            int pos = __popcll((bal >> sh) & 0xFFFFull);
            unsigned long long up = __shfl_up(listkey, 1, 16);
            if (lane16 == pos) listkey = mv;
            else if (lane16 > pos) listkey = up;
        }
    }
    pkeys[(((size_t)(b * P + i0 + row)) * NCH + chunk) * 16 + lane16] = listkey;
}

// ---- exact merge of per-chunk sorted top-16 lists -> final top-16 ----------
__global__ void __launch_bounds__(256) k_knn_merge(const unsigned long long* __restrict__ pkeys,
                                                   int* __restrict__ nbr) {
    int tid = threadIdx.x;
    int lane = tid & 63, w = tid >> 6;
    int g = lane >> 4, lane16 = lane & 15;
    int row = blockIdx.x * 16 + w * 4 + g;
    int sh = lane & 48;
    // chunk 0's list is already sorted descending across lane16
    unsigned long long listkey = pkeys[((size_t)row * NCH + 0) * 16 + lane16];
    #pragma unroll
    for (int s = 1; s < NCH; s++) {
        unsigned long long cand = pkeys[((size_t)row * NCH + s) * 16 + lane16];
        unsigned long long lmin = __shfl(listkey, 15, 16);
        unsigned long long bal = __ballot(cand > lmin);
        unsigned long long gm = (bal >> sh) & 0xFFFFull;
        while (gm) {
            int src = __builtin_ctzll(gm);
            gm &= gm - 1;
            unsigned long long mv = __shfl(cand, src, 16);
            unsigned long long bal2 = __ballot(listkey > mv);
            int pos = __popcll((bal2 >> sh) & 0xFFFFull);
            unsigned long long up = __shfl_up(listkey, 1, 16);
            if (lane16 == pos) listkey = mv;       // stale cand: pos==16 -> no-op
            else if (lane16 > pos) listkey = up;
        }
    }
    nbr[(size_t)row * KNN + lane16] = 1023 - (int)(listkey & 0xFFFFFFFFull);
}

// ---------------- UV projection: [16384, D] @ [D, 192] ----------------
__global__ void k_uv(const float* __restrict__ Hout, int colOff, int D,
                     const float* __restrict__ WUV, float* __restrict__ UV) {
    __shared__ float Xt[16 * 192];
    int tid = threadIdx.x;   // 192 threads
    int p0 = blockIdx.x * 16;
    for (int idx = tid; idx < 16 * D; idx += 192) {
        int r = idx / D, d = idx - r * D;
        Xt[r * 192 + d] = Hout[(p0 + r) * 256 + colOff + d];
    }
    __syncthreads();
    float acc[16];
    #pragma unroll
    for (int p = 0; p < 16; p++) acc[p] = 0.f;
    for (int k = 0; k < D; k++) {
        float w = WUV[k * 192 + tid];
        #pragma unroll
        for (int p = 0; p < 16; p++) acc[p] += Xt[p * 192 + k] * w;
    }
    #pragma unroll
    for (int p = 0; p < 16; p++) UV[(size_t)(p0 + p) * 192 + tid] = acc[p];
}

// ------ per-edge message kernel: hoisted nbrs, batched mut, Uj prefetch -----
__global__ void __launch_bounds__(256) k_edge(const float* __restrict__ UV, const int* __restrict__ nbr,
                                              const float* __restrict__ wb, const float* __restrict__ bbv,
                                              const float* __restrict__ cvec, int colOut,
                                              float* __restrict__ Hout) {
    __shared__ __align__(16) float m1s[4][2][96];   // wave-private fwd/rev buffers
    __shared__ float cvs[96];
    __shared__ float bbs[64];
    int tid = threadIdx.x;
    int w = tid >> 6, lane = tid & 63;
    float wreg[96];                              // wb column `lane` in registers
    #pragma unroll
    for (int k = 0; k < 96; k++) wreg[k] = wb[k * 64 + lane];
    if (tid < 96) cvs[tid] = cvec[tid];
    if (tid < 64) bbs[tid] = bbv[tid];
    int ifl = blockIdx.x * 4 + w;
    int b = ifl >> 10, i = ifl & 1023;
    const float* Ui = UV + (size_t)ifl * 192;
    float ui0 = Ui[lane];
    float ui1 = (lane < 32) ? Ui[64 + lane] : 0.f;
    float vi0 = Ui[96 + lane];
    float vi1 = (lane < 32) ? Ui[160 + lane] : 0.f;
    // hoist all 16 neighbor indices (lanes 0-15 authoritative, shfl-broadcast)
    int jv = nbr[ifl * KNN + (lane & 15)];
    // batched mutuality: lane l checks entries 4*(l&3)..+3 of knn(j_{l>>2})
    int jk = __shfl(jv, lane >> 2, 64);
    const int4* nb4p = (const int4*)(nbr + ((size_t)b * P + jk) * KNN + (lane & 3) * 4);
    int4 nb4 = *nb4p;
    bool hit = (nb4.x == i) | (nb4.y == i) | (nb4.z == i) | (nb4.w == i);
    unsigned long long mb = __ballot(hit);
    mb |= (mb >> 1); mb |= (mb >> 2);            // bit 4k = any of bits 4k..4k+3
    float accA = 0.f;
    __syncthreads();
    float bbl = bbs[lane];
    float cv0 = cvs[lane];
    float cv1 = (lane < 32) ? cvs[64 + lane] : 0.f;
    const float4* mf4 = (const float4*)m1s[w][0];
    const float4* mr4 = (const float4*)m1s[w][1];
    // prefetch neighbor 0's U/V rows
    int jf = b * P + __shfl(jv, 0, 64);
    const float* Uj = UV + (size_t)jf * 192;
    float pu0 = Uj[lane];
    float pu1 = (lane < 32) ? Uj[64 + lane] : 0.f;
    float pv0 = Uj[96 + lane];
    float pv1 = (lane < 32) ? Uj[160 + lane] : 0.f;
    for (int kk = 0; kk < KNN; kk++) {
        float cu0 = pu0, cu1 = pu1, cw0 = pv0, cw1 = pv1;
        int jfc = jf;
        if (kk + 1 < KNN) {                      // issue next gather early (G7)
            jf = b * P + __shfl(jv, kk + 1, 64);
            const float* Un = UV + (size_t)jf * 192;
            pu0 = Un[lane];
            pu1 = (lane < 32) ? Un[64 + lane] : 0.f;
            pv0 = Un[96 + lane];
            pv1 = (lane < 32) ? Un[160 + lane] : 0.f;
        }
        // both messages written, single LDS round-trip (wave-private, no barrier)
        m1s[w][0][lane] = fmaxf(ui0 + cw0 + cv0, 0.f);
        m1s[w][1][lane] = fmaxf(cu0 + vi0 + cv0, 0.f);
        if (lane < 32) {
            m1s[w][0][64 + lane] = fmaxf(ui1 + cw1 + cv1, 0.f);
            m1s[w][1][64 + lane] = fmaxf(cu1 + vi1 + cv1, 0.f);
        }
        float t = bbl, t2 = bbl;
        #pragma unroll
        for (int k4 = 0; k4 < 24; k4++) {
            float4 a = mf4[k4];
            float4 r = mr4[k4];
            t  += a.x * wreg[k4 * 4 + 0];
            t2 += r.x * wreg[k4 * 4 + 0];
            t  += a.y * wreg[k4 * 4 + 1];
            t2 += r.y * wreg[k4 * 4 + 1];
            t  += a.z * wreg[k4 * 4 + 2];
            t2 += r.z * wreg[k4 * 4 + 2];
            t  += a.w * wreg[k4 * 4 + 3];
            t2 += r.w * wreg[k4 * 4 + 3];
        }
        accA += fmaxf(t, 0.f);
        if (!((mb >> (4 * kk)) & 1))
            atomicAdd(&Hout[(size_t)jfc * 256 + colOut + lane], fmaxf(t2, 0.f));
    }
    atomicAdd(&Hout[(size_t)ifl * 256 + colOut + lane], accA);
}

// ---------------- global max pool (partial) ----------------
__global__ void k_pool(const float* __restrict__ Hout, float* __restrict__ part) {
    int tid = threadIdx.x;
    int b = blockIdx.x >> 4, pt = blockIdx.x & 15;
    float mv = -1e30f;
    for (int p = pt * 64; p < pt * 64 + 64; p++)
        mv = fmaxf(mv, Hout[(size_t)(b * P + p) * 256 + tid]);
    part[(b * 16 + pt) * 256 + tid] = mv;
}

// ---------------- final reduce + output MLP ----------------
__global__ void k_out(const float* __restrict__ part,
                      const float* __restrict__ w1, const float* __restrict__ b1,
                      const float* __restrict__ w2, const float* __restrict__ b2,
                      const float* __restrict__ w3, const float* __restrict__ b3,
                      float* __restrict__ out) {
    __shared__ float pooled[256];
    __shared__ float r1[128];
    __shared__ float r2[32];
    int tid = threadIdx.x, b = blockIdx.x;
    float mv = -1e30f;
    for (int t = 0; t < 16; t++) mv = fmaxf(mv, part[(b * 16 + t) * 256 + tid]);
    pooled[tid] = mv;
    __syncthreads();
    if (tid < 128) {
        float a = b1[tid];
        for (int k = 0; k < 256; k++) a += pooled[k] * w1[k * 128 + tid];
        r1[tid] = fmaxf(a, 0.f);
    }
    __syncthreads();
    if (tid < 32) {
        float a = b2[tid];
        for (int k = 0; k < 128; k++) a += r1[k] * w2[k * 32 + tid];
        r2[tid] = fmaxf(a, 0.f);
    }
    __syncthreads();
    if (tid == 0) {
        float a = b3[0];
        for (int k = 0; k < 32; k++) a += r2[k] * w3[k];
        out[b] = a;
    }
}

extern "C" void kernel_launch(void* const* d_in, const int* in_sizes, int n_in,
                              void* d_out, int out_size, void* d_ws, size_t ws_size,
                              hipStream_t stream) {
    const float* x  = (const float*)d_in[0];
    const float* dn = (const float*)d_in[1];
    float* out = (float*)d_out;
    float* Hout = out + 16;           // [16384][256] feature/output buffer
    float* ws = (float*)d_ws;
    float* UV   = ws + WS_UV;
    float* rn   = ws + WS_RN;
    int*   nbr  = (int*)(ws + WS_NBR);
    float* WUV  = ws + WS_WUV;
    float* cvec = ws + WS_CVEC;
    float* part = ws + WS_PART;
    float* Xt   = ws + WS_XT;
    unsigned long long* pkeys = (unsigned long long*)UV;   // aliased: dead before k_uv

    hipMemsetAsync(d_out, 0, (size_t)out_size * sizeof(float), stream);

    k_input<<<2048, 128, 0, stream>>>(x, dn,
        (const float*)d_in[2], (const float*)d_in[3],
        (const float*)d_in[4], (const float*)d_in[5],
        (const float*)d_in[6], (const float*)d_in[7], Hout);

    const int convOff[3] = {192, 128, 64};   // input column offset
    const int convD[3]   = {64, 128, 192};   // input feature width
    const int convOut[3] = {128, 64, 0};     // output column offset
    for (int c = 0; c < 3; c++) {
        int pb = 8 + c * 8;
        const float* wa  = (const float*)d_in[pb + 0];
        const float* ba  = (const float*)d_in[pb + 1];
        const float* g   = (const float*)d_in[pb + 2];
        const float* bB  = (const float*)d_in[pb + 3];
        const float* m   = (const float*)d_in[pb + 4];
        const float* v   = (const float*)d_in[pb + 5];
        const float* wb  = (const float*)d_in[pb + 6];
        const float* bbv = (const float*)d_in[pb + 7];
        int D = convD[c], off = convOff[c], co = convOut[c];
        k_prep<<<(D * 192 + 255) / 256, 256, 0, stream>>>(wa, ba, g, bB, m, v, D, WUV, cvec);
        k_rn<<<64, 256, 0, stream>>>(Hout, off, D, rn);
        k_tr<<<dim3(D / 64, P / 64, B), 256, 0, stream>>>(Hout, off, D, Xt);
        if (c == 0)      k_knn3<64><<<4096, 256, 0, stream>>>(Xt, rn, pkeys);
        else if (c == 1) k_knn3<128><<<4096, 256, 0, stream>>>(Xt, rn, pkeys);
        else             k_knn3<192><<<4096, 256, 0, stream>>>(Xt, rn, pkeys);
        k_knn_merge<<<1024, 256, 0, stream>>>(pkeys, nbr);
        k_uv<<<1024, 192, 0, stream>>>(Hout, off, D, WUV, UV);
        k_edge<<<4096, 256, 0, stream>>>(UV, nbr, wb, bbv, cvec, co, Hout);
    }

    k_pool<<<256, 256, 0, stream>>>(Hout, part);
    k_out<<<16, 256, 0, stream>>>(part,
        (const float*)d_in[32], (const float*)d_in[33],
        (const float*)d_in[34], (const float*)d_in[35],
        (const float*)d_in[36], (const float*)d_in[37], out);
}

// Round 11
// 1114.521 us; speedup vs baseline: 3.9852x; 1.0281x over previous
//
#include <hip/hip_runtime.h>
#include <hip/hip_bf16.h>

#define B 16
#define P 1024
#define NPT 16384   // B*P
#define KNN 16
#define MID 96
#define HD 64

// ws layout (in floats)
#define WS_UV   0                        // NPT*192  (aliased as pkeys: NPT*4*16 u64 = 8.4MB < 12.58MB)
#define WS_RN   (WS_UV + NPT*192)        // NPT
#define WS_NBR  (WS_RN + NPT)            // NPT*KNN ints
#define WS_WUV  (WS_NBR + NPT*KNN)       // up to 192*192
#define WS_CVEC (WS_WUV + 192*192)       // 96
#define WS_PART (WS_CVEC + 96)           // B*16*256
#define WS_XT   (WS_PART + 16*16*256)    // B*192*1024 floats (transposed features)

#define NCH 4        // chunk lists per row

typedef float f32x2 __attribute__((ext_vector_type(2)));

// ---------------- input MLP: 5 -> 128 -> 128 -> 64, writes cols 192..255 ----
__global__ void k_input(const float* __restrict__ x, const float* __restrict__ dn,
                        const float* __restrict__ w1, const float* __restrict__ b1,
                        const float* __restrict__ w2, const float* __restrict__ b2,
                        const float* __restrict__ w3, const float* __restrict__ b3,
                        float* __restrict__ Hout) {
    __shared__ float xs[8][5];
    __shared__ float t1[8][128];
    __shared__ float t2[8][128];
    int tid = threadIdx.x;            // 128 threads
    int p0 = blockIdx.x * 8;
    if (tid < 40) { int p = tid / 5, f = tid - p * 5; xs[p][f] = x[(p0 + p) * 5 + f] * dn[f]; }
    __syncthreads();
    int c = tid;
    {
        float bb = b1[c];
        #pragma unroll
        for (int p = 0; p < 8; p++) {
            float a = bb;
            #pragma unroll
            for (int f = 0; f < 5; f++) a += xs[p][f] * w1[f * 128 + c];
            t1[p][c] = fmaxf(a, 0.f);
        }
    }
    __syncthreads();
    {
        float acc[8];
        float bb = b2[c];
        #pragma unroll
        for (int p = 0; p < 8; p++) acc[p] = bb;
        for (int k = 0; k < 128; k++) {
            float w = w2[k * 128 + c];
            #pragma unroll
            for (int p = 0; p < 8; p++) acc[p] += t1[p][k] * w;
        }
        #pragma unroll
        for (int p = 0; p < 8; p++) t2[p][c] = fmaxf(acc[p], 0.f);
    }
    __syncthreads();
    if (c < 64) {
        float acc[8];
        float bb = b3[c];
        #pragma unroll
        for (int p = 0; p < 8; p++) acc[p] = bb;
        for (int k = 0; k < 128; k++) {
            float w = w3[k * 64 + c];
            #pragma unroll
            for (int p = 0; p < 8; p++) acc[p] += t2[p][k] * w;
        }
        #pragma unroll
        for (int p = 0; p < 8; p++) Hout[(p0 + p) * 256 + 192 + c] = fmaxf(acc[p], 0.f);
    }
}

// ---------------- per-conv weight prep: WUV = [(top-bot)*s | bot*s], cvec ----
__global__ void k_prep(const float* __restrict__ wa, const float* __restrict__ ba,
                       const float* __restrict__ g, const float* __restrict__ bB,
                       const float* __restrict__ m, const float* __restrict__ v,
                       int D, float* __restrict__ WUV, float* __restrict__ cvec) {
    int idx = blockIdx.x * 256 + threadIdx.x;
    if (idx < D * 192) {
        int k = idx / 192, col = idx - k * 192;
        int ch = (col < 96) ? col : col - 96;
        float s = g[ch] * rsqrtf(v[ch] + 1e-5f);
        float w = (col < 96) ? (wa[k * 96 + ch] - wa[(D + k) * 96 + ch]) : wa[(D + k) * 96 + ch];
        WUV[idx] = w * s;
    }
    if (blockIdx.x == 0 && threadIdx.x < 96) {
        int ch = threadIdx.x;
        float s = g[ch] * rsqrtf(v[ch] + 1e-5f);
        cvec[ch] = ba[ch] * s + (bB[ch] - m[ch] * s);
    }
}

// ---------------- row inverse norms ----------------
__global__ void k_rn(const float* __restrict__ Hout, int colOff, int D, float* __restrict__ rn) {
    int p = blockIdx.x * 256 + threadIdx.x;
    if (p >= NPT) return;
    const float* r = Hout + p * 256 + colOff;
    float ss = 0.f;
    for (int d = 0; d < D; d++) { float v = r[d]; ss += v * v; }
    rn[p] = rsqrtf(ss + 1e-12f);
}

// ---------------- per-batch feature transpose: Xt[b][d][1024] ----------------
__global__ void __launch_bounds__(256) k_tr(const float* __restrict__ Hout, int colOff, int D,
                                            float* __restrict__ Xt) {
    __shared__ float t[64][65];
    int tid = threadIdx.x;
    int d0 = blockIdx.x * 64, p0 = blockIdx.y * 64, b = blockIdx.z;
    int r4 = tid >> 6, c = tid & 63;
    #pragma unroll
    for (int k = 0; k < 16; k++) {
        int row = k * 4 + r4;
        t[row][c] = Hout[(size_t)(b * P + p0 + row) * 256 + colOff + d0 + c];
    }
    __syncthreads();
    #pragma unroll
    for (int k = 0; k < 16; k++) {
        int d = k * 4 + r4;
        Xt[((size_t)b * D + d0 + d) * 1024 + p0 + c] = t[c][d];
    }
}

// ------ GEMM-style cosine-sim (coalesced Xt, packed f32x2 FMA) + blind-insert
#define ST_LD 272

__device__ __forceinline__ unsigned long long packkey(float v, int q) {
    unsigned u = __float_as_uint(v);
    u = (u & 0x80000000u) ? ~u : (u | 0x80000000u);
    return ((unsigned long long)u << 32) | (unsigned)(1023 - q);
}

template<int D>
__global__ void __launch_bounds__(256) k_knn3(const float* __restrict__ Xt,
                                              const float* __restrict__ rn,
                                              unsigned long long* __restrict__ pkeys) {
    __shared__ __align__(16) float XiT[D * 20];          // [d][16 rows], pad 20
    __shared__ __align__(16) float simtile[16 * ST_LD];  // [16 rows][256 cands]
    int tid = threadIdx.x;
    int chunk = blockIdx.x & 3, rt = (blockIdx.x >> 2) & 63, b = blockIdx.x >> 8;
    int i0 = rt * 16, q0 = chunk * 256;
    int lane = tid & 63, w = tid >> 6;
    // stage XiT (row tile, transposed)
    for (int idx = tid; idx < 16 * D; idx += 256) {
        int d = idx >> 4, r = idx & 15;
        XiT[d * 20 + r] = Xt[((size_t)b * D + d) * 1024 + i0 + r];
    }
    __syncthreads();
    // ---- compute: thread = rows 4w..4w+3 x cands q0+4*lane..+3 ----
    // packed-pair accumulators: accA[r]=(sim[r][0],sim[r][1]) accB[r]=(..2,..3)
    // each half is an independent scalar chain in ascending-d order ->
    // bit-identical to scalar version; compiler emits v_pk_fma_f32.
    const float* cvb = Xt + (size_t)b * D * 1024 + q0 + 4 * lane;
    f32x2 accA[4] = {}, accB[4] = {};
    #pragma unroll 8
    for (int d = 0; d < D; d++) {
        float4 cv = *(const float4*)(cvb + (size_t)d * 1024);
        float4 rv = *(const float4*)(XiT + d * 20 + 4 * w);
        f32x2 cA = {cv.x, cv.y}, cB = {cv.z, cv.w};
        f32x2 r0 = {rv.x, rv.x}, r1 = {rv.y, rv.y};
        f32x2 r2 = {rv.z, rv.z}, r3 = {rv.w, rv.w};
        accA[0] += r0 * cA; accB[0] += r0 * cB;
        accA[1] += r1 * cA; accB[1] += r1 * cB;
        accA[2] += r2 * cA; accB[2] += r2 * cB;
        accA[3] += r3 * cA; accB[3] += r3 * cB;
    }
    float4 rq = *(const float4*)(rn + b * P + q0 + 4 * lane);
    int qg = q0 + 4 * lane;
    #pragma unroll
    for (int r = 0; r < 4; r++) {
        float rnir = rn[b * P + i0 + 4 * w + r];
        int ig = i0 + 4 * w + r;
        float4 v;
        v.x = accA[r].x * rnir * rq.x;
        v.y = accA[r].y * rnir * rq.y;
        v.z = accB[r].x * rnir * rq.z;
        v.w = accB[r].y * rnir * rq.w;
        if (qg + 0 == ig) v.x = -1e9f;
        if (qg + 1 == ig) v.y = -1e9f;
        if (qg + 2 == ig) v.z = -1e9f;
        if (qg + 3 == ig) v.w = -1e9f;
        *(float4*)(simtile + (4 * w + r) * ST_LD + 4 * lane) = v;
    }
    __syncthreads();
    // ---- R4 ballot-filter + blind-insert: 16-lane group per row, 4 tiles ----
    int g = lane >> 4, lane16 = lane & 15;
    int row = w * 4 + g;
    int sh = lane & 48;
    unsigned long long listkey = 0ull;
    for (int t = 0; t < 4; t++) {
        int qb = q0 + t * 64;
        unsigned long long c0 = packkey(simtile[row * ST_LD + t * 64 + lane16     ], qb + lane16);
        unsigned long long c1 = packkey(simtile[row * ST_LD + t * 64 + lane16 + 16], qb + lane16 + 16);
        unsigned long long c2 = packkey(simtile[row * ST_LD + t * 64 + lane16 + 32], qb + lane16 + 32);
        unsigned long long c3 = packkey(simtile[row * ST_LD + t * 64 + lane16 + 48], qb + lane16 + 48);
        unsigned long long lmin = __shfl(listkey, 15, 16);
        unsigned long long b0 = __ballot(c0 > lmin);
        unsigned long long b1 = __ballot(c1 > lmin);
        unsigned long long b2 = __ballot(c2 > lmin);
        unsigned long long b3 = __ballot(c3 > lmin);
        unsigned long long gm = ((b0 >> sh) & 0xFFFFull)
                              | (((b1 >> sh) & 0xFFFFull) << 16)
                              | (((b2 >> sh) & 0xFFFFull) << 32)
                              | (((b3 >> sh) & 0xFFFFull) << 48);
        // stale (too-small) candidates self-discard (pos==16 -> no-op)
        while (gm) {
            int pb = __builtin_ctzll(gm);
            gm &= gm - 1;
            int slot = pb >> 4, src = pb & 15;
            unsigned long long sel = (slot & 2) ? ((slot & 1) ? c3 : c2)
                                                : ((slot & 1) ? c1 : c0);
            unsigned long long mv = __shfl(sel, src, 16);
            unsigned long long bal = __ballot(listkey > mv);
            int pos = __popcll((bal >> sh) & 0xFFFFull);
            unsigned long long up = __shfl_up(listkey, 1, 16);
            if (lane16 == pos) listkey = mv;
            else if (lane16 > pos) listkey = up;
        }
    }
    pkeys[(((size_t)(b * P + i0 + row)) * NCH + chunk) * 16 + lane16] = listkey;
}

// ---- exact merge of per-chunk sorted top-16 lists -> final top-16 ----------
__global__ void __launch_bounds__(256) k_knn_merge(const unsigned long long* __restrict__ pkeys,
                                                   int* __restrict__ nbr) {
    int tid = threadIdx.x;
    int lane = tid & 63, w = tid >> 6;
    int g = lane >> 4, lane16 = lane & 15;
    int row = blockIdx.x * 16 + w * 4 + g;
    int sh = lane & 48;
    // chunk 0's list is already sorted descending across lane16
    unsigned long long listkey = pkeys[((size_t)row * NCH + 0) * 16 + lane16];
    #pragma unroll
    for (int s = 1; s < NCH; s++) {
        unsigned long long cand = pkeys[((size_t)row * NCH + s) * 16 + lane16];
        unsigned long long lmin = __shfl(listkey, 15, 16);
        unsigned long long bal = __ballot(cand > lmin);
        unsigned long long gm = (bal >> sh) & 0xFFFFull;
        while (gm) {
            int src = __builtin_ctzll(gm);
            gm &= gm - 1;
            unsigned long long mv = __shfl(cand, src, 16);
            unsigned long long bal2 = __ballot(listkey > mv);
            int pos = __popcll((bal2 >> sh) & 0xFFFFull);
            unsigned long long up = __shfl_up(listkey, 1, 16);
            if (lane16 == pos) listkey = mv;       // stale cand: pos==16 -> no-op
            else if (lane16 > pos) listkey = up;
        }
    }
    nbr[(size_t)row * KNN + lane16] = 1023 - (int)(listkey & 0xFFFFFFFFull);
}

// ---------------- UV projection: [16384, D] @ [D, 192] ----------------
__global__ void k_uv(const float* __restrict__ Hout, int colOff, int D,
                     const float* __restrict__ WUV, float* __restrict__ UV) {
    __shared__ float Xt[16 * 192];
    int tid = threadIdx.x;   // 192 threads
    int p0 = blockIdx.x * 16;
    for (int idx = tid; idx < 16 * D; idx += 192) {
        int r = idx / D, d = idx - r * D;
        Xt[r * 192 + d] = Hout[(p0 + r) * 256 + colOff + d];
    }
    __syncthreads();
    float acc[16];
    #pragma unroll
    for (int p = 0; p < 16; p++) acc[p] = 0.f;
    for (int k = 0; k < D; k++) {
        float w = WUV[k * 192 + tid];
        #pragma unroll
        for (int p = 0; p < 16; p++) acc[p] += Xt[p * 192 + k] * w;
    }
    #pragma unroll
    for (int p = 0; p < 16; p++) UV[(size_t)(p0 + p) * 192 + tid] = acc[p];
}

// ------ per-edge message kernel: hoisted nbrs, batched mut, Uj prefetch -----
__global__ void __launch_bounds__(256) k_edge(const float* __restrict__ UV, const int* __restrict__ nbr,
                                              const float* __restrict__ wb, const float* __restrict__ bbv,
                                              const float* __restrict__ cvec, int colOut,
                                              float* __restrict__ Hout) {
    __shared__ __align__(16) float m1s[4][2][96];   // wave-private fwd/rev buffers
    __shared__ float cvs[96];
    __shared__ float bbs[64];
    int tid = threadIdx.x;
    int w = tid >> 6, lane = tid & 63;
    float wreg[96];                              // wb column `lane` in registers
    #pragma unroll
    for (int k = 0; k < 96; k++) wreg[k] = wb[k * 64 + lane];
    if (tid < 96) cvs[tid] = cvec[tid];
    if (tid < 64) bbs[tid] = bbv[tid];
    int ifl = blockIdx.x * 4 + w;
    int b = ifl >> 10, i = ifl & 1023;
    const float* Ui = UV + (size_t)ifl * 192;
    float ui0 = Ui[lane];
    float ui1 = (lane < 32) ? Ui[64 + lane] : 0.f;
    float vi0 = Ui[96 + lane];
    float vi1 = (lane < 32) ? Ui[160 + lane] : 0.f;
    // hoist all 16 neighbor indices (lanes 0-15 authoritative, shfl-broadcast)
    int jv = nbr[ifl * KNN + (lane & 15)];
    // batched mutuality: lane l checks entries 4*(l&3)..+3 of knn(j_{l>>2})
    int jk = __shfl(jv, lane >> 2, 64);
    const int4* nb4p = (const int4*)(nbr + ((size_t)b * P + jk) * KNN + (lane & 3) * 4);
    int4 nb4 = *nb4p;
    bool hit = (nb4.x == i) | (nb4.y == i) | (nb4.z == i) | (nb4.w == i);
    unsigned long long mb = __ballot(hit);
    mb |= (mb >> 1); mb |= (mb >> 2);            // bit 4k = any of bits 4k..4k+3
    float accA = 0.f;
    __syncthreads();
    float bbl = bbs[lane];
    float cv0 = cvs[lane];
    float cv1 = (lane < 32) ? cvs[64 + lane] : 0.f;
    const float4* mf4 = (const float4*)m1s[w][0];
    const float4* mr4 = (const float4*)m1s[w][1];
    // prefetch neighbor 0's U/V rows
    int jf = b * P + __shfl(jv, 0, 64);
    const float* Uj = UV + (size_t)jf * 192;
    float pu0 = Uj[lane];
    float pu1 = (lane < 32) ? Uj[64 + lane] : 0.f;
    float pv0 = Uj[96 + lane];
    float pv1 = (lane < 32) ? Uj[160 + lane] : 0.f;
    for (int kk = 0; kk < KNN; kk++) {
        float cu0 = pu0, cu1 = pu1, cw0 = pv0, cw1 = pv1;
        int jfc = jf;
        if (kk + 1 < KNN) {                      // issue next gather early (G7)
            jf = b * P + __shfl(jv, kk + 1, 64);
            const float* Un = UV + (size_t)jf * 192;
            pu0 = Un[lane];
            pu1 = (lane < 32) ? Un[64 + lane] : 0.f;
            pv0 = Un[96 + lane];
            pv1 = (lane < 32) ? Un[160 + lane] : 0.f;
        }
        // both messages written, single LDS round-trip (wave-private, no barrier)
        m1s[w][0][lane] = fmaxf(ui0 + cw0 + cv0, 0.f);
        m1s[w][1][lane] = fmaxf(cu0 + vi0 + cv0, 0.f);
        if (lane < 32) {
            m1s[w][0][64 + lane] = fmaxf(ui1 + cw1 + cv1, 0.f);
            m1s[w][1][64 + lane] = fmaxf(cu1 + vi1 + cv1, 0.f);
        }
        float t = bbl, t2 = bbl;
        #pragma unroll
        for (int k4 = 0; k4 < 24; k4++) {
            float4 a = mf4[k4];
            float4 r = mr4[k4];
            t  += a.x * wreg[k4 * 4 + 0];
            t2 += r.x * wreg[k4 * 4 + 0];
            t  += a.y * wreg[k4 * 4 + 1];
            t2 += r.y * wreg[k4 * 4 + 1];
            t  += a.z * wreg[k4 * 4 + 2];
            t2 += r.z * wreg[k4 * 4 + 2];
            t  += a.w * wreg[k4 * 4 + 3];
            t2 += r.w * wreg[k4 * 4 + 3];
        }
        accA += fmaxf(t, 0.f);
        if (!((mb >> (4 * kk)) & 1))
            atomicAdd(&Hout[(size_t)jfc * 256 + colOut + lane], fmaxf(t2, 0.f));
    }
    atomicAdd(&Hout[(size_t)ifl * 256 + colOut + lane], accA);
}

// ---------------- global max pool (partial) ----------------
__global__ void k_pool(const float* __restrict__ Hout, float* __restrict__ part) {
    int tid = threadIdx.x;
    int b = blockIdx.x >> 4, pt = blockIdx.x & 15;
    float mv = -1e30f;
    for (int p = pt * 64; p < pt * 64 + 64; p++)
        mv = fmaxf(mv, Hout[(size_t)(b * P + p) * 256 + tid]);
    part[(b * 16 + pt) * 256 + tid] = mv;
}

// ---------------- final reduce + output MLP ----------------
__global__ void k_out(const float* __restrict__ part,
                      const float* __restrict__ w1, const float* __restrict__ b1,
                      const float* __restrict__ w2, const float* __restrict__ b2,
                      const float* __restrict__ w3, const float* __restrict__ b3,
                      float* __restrict__ out) {
    __shared__ float pooled[256];
    __shared__ float r1[128];
    __shared__ float r2[32];
    int tid = threadIdx.x, b = blockIdx.x;
    float mv = -1e30f;
    for (int t = 0; t < 16; t++) mv = fmaxf(mv, part[(b * 16 + t) * 256 + tid]);
    pooled[tid] = mv;
    __syncthreads();
    if (tid < 128) {
        float a = b1[tid];
        for (int k = 0; k < 256; k++) a += pooled[k] * w1[k * 128 + tid];
        r1[tid] = fmaxf(a, 0.f);
    }
    __syncthreads();
    if (tid < 32) {
        float a = b2[tid];
        for (int k = 0; k < 128; k++) a += r1[k] * w2[k * 32 + tid];
        r2[tid] = fmaxf(a, 0.f);
    }
    __syncthreads();
    if (tid == 0) {
        float a = b3[0];
        for (int k = 0; k < 32; k++) a += r2[k] * w3[k];
        out[b] = a;
    }
}

extern "C" void kernel_launch(void* const* d_in, const int* in_sizes, int n_in,
                              void* d_out, int out_size, void* d_ws, size_t ws_size,
                              hipStream_t stream) {
    const float* x  = (const float*)d_in[0];
    const float* dn = (const float*)d_in[1];
    float* out = (float*)d_out;
    float* Hout = out + 16;           // [16384][256] feature/output buffer
    float* ws = (float*)d_ws;
    float* UV   = ws + WS_UV;
    float* rn   = ws + WS_RN;
    int*   nbr  = (int*)(ws + WS_NBR);
    float* WUV  = ws + WS_WUV;
    float* cvec = ws + WS_CVEC;
    float* part = ws + WS_PART;
    float* Xt   = ws + WS_XT;
    unsigned long long* pkeys = (unsigned long long*)UV;   // aliased: dead before k_uv

    hipMemsetAsync(d_out, 0, (size_t)out_size * sizeof(float), stream);

    k_input<<<2048, 128, 0, stream>>>(x, dn,
        (const float*)d_in[2], (const float*)d_in[3],
        (const float*)d_in[4], (const float*)d_in[5],
        (const float*)d_in[6], (const float*)d_in[7], Hout);

    const int convOff[3] = {192, 128, 64};   // input column offset
    const int convD[3]   = {64, 128, 192};   // input feature width
    const int convOut[3] = {128, 64, 0};     // output column offset
    for (int c = 0; c < 3; c++) {
        int pb = 8 + c * 8;
        const float* wa  = (const float*)d_in[pb + 0];
        const float* ba  = (const float*)d_in[pb + 1];
        const float* g   = (const float*)d_in[pb + 2];
        const float* bB  = (const float*)d_in[pb + 3];
        const float* m   = (const float*)d_in[pb + 4];
        const float* v   = (const float*)d_in[pb + 5];
        const float* wb  = (const float*)d_in[pb + 6];
        const float* bbv = (const float*)d_in[pb + 7];
        int D = convD[c], off = convOff[c], co = convOut[c];
        k_prep<<<(D * 192 + 255) / 256, 256, 0, stream>>>(wa, ba, g, bB, m, v, D, WUV, cvec);
        k_rn<<<64, 256, 0, stream>>>(Hout, off, D, rn);
        k_tr<<<dim3(D / 64, P / 64, B), 256, 0, stream>>>(Hout, off, D, Xt);
        if (c == 0)      k_knn3<64><<<4096, 256, 0, stream>>>(Xt, rn, pkeys);
        else if (c == 1) k_knn3<128><<<4096, 256, 0, stream>>>(Xt, rn, pkeys);
        else             k_knn3<192><<<4096, 256, 0, stream>>>(Xt, rn, pkeys);
        k_knn_merge<<<1024, 256, 0, stream>>>(pkeys, nbr);
        k_uv<<<1024, 192, 0, stream>>>(Hout, off, D, WUV, UV);
        k_edge<<<4096, 256, 0, stream>>>(UV, nbr, wb, bbv, cvec, co, Hout);
    }

    k_pool<<<256, 256, 0, stream>>>(Hout, part);
    k_out<<<16, 256, 0, stream>>>(part,
        (const float*)d_in[32], (const float*)d_in[33],
        (const float*)d_in[34], (const float*)d_in[35],
        (const float*)d_in[36], (const float*)d_in[37], out);
}